// Round 1
// baseline (274.460 us; speedup 1.0000x reference)
//
#include <hip/hip_runtime.h>

#define NODES 4096

typedef float f32x4 __attribute__((ext_vector_type(4)));
typedef __bf16 bf16x8 __attribute__((ext_vector_type(8)));
typedef unsigned short u16x8 __attribute__((ext_vector_type(8)));
typedef unsigned short u16x4 __attribute__((ext_vector_type(4)));

__device__ __forceinline__ unsigned short f2bf(float x) {
    unsigned u = __builtin_bit_cast(unsigned, x);
    return (unsigned short)((u + 0x7fffu + ((u >> 16) & 1u)) >> 16);
}

// ---- stage A: h = tanh(x@Wm + bm), stored transposed bf16 [64][4096] -------
__global__ __launch_bounds__(256) void prep_h(
    const float* __restrict__ f0, const float* __restrict__ f1,
    const float* __restrict__ Wm0, const float* __restrict__ bm0,
    const float* __restrict__ Wm1, const float* __restrict__ bm1,
    unsigned short* __restrict__ hT0, unsigned short* __restrict__ hT1)
{
    const int d = threadIdx.x & 63;
    int n = blockIdx.x * 4 + (threadIdx.x >> 6);
    n = __builtin_amdgcn_readfirstlane(n);   // wave-uniform -> s_loads of the feature row
    const float* r0 = f0 + (size_t)n * 256;
    float a0 = bm0[d];
#pragma unroll 8
    for (int k = 0; k < 256; ++k) a0 = fmaf(r0[k], Wm0[k * 64 + d], a0);
    hT0[(size_t)d * NODES + n] = f2bf(tanhf(a0));
    const float* r1 = f1 + (size_t)n * 128;
    float a1 = bm1[d];
#pragma unroll 8
    for (int k = 0; k < 128; ++k) a1 = fmaf(r1[k], Wm1[k * 64 + d], a1);
    hT1[(size_t)d * NODES + n] = f2bf(tanhf(a1));
}

// ---- adjacency GEMM: C[job] = (tanh?)(A[job] @ H),  A f32 [4096,4096], H via hT bf16 [64][4096]
// BM=16 rows/block, BK=64. 256 thr = 4 waves, wave w computes 16x16 output tile (cols w*16..).
// LDS tiles XOR-swizzled: byte ^= (row&7)<<4  -> ds_read_b128 fragments ~conflict-free.
__global__ __launch_bounds__(256, 5) void adj_gemm(
    const float* __restrict__ A0, const float* __restrict__ A1,
    const float* __restrict__ A2, const float* __restrict__ A3,
    const float* __restrict__ A4,
    const unsigned short* __restrict__ hTa, const unsigned short* __restrict__ hTb,
    int split, float* __restrict__ outBase, unsigned tanhMask)
{
    constexpr int BK = 64;
    constexpr int NT = NODES / BK;
    __shared__ unsigned short Al[2][16 * BK];   // 2 KB each buf
    __shared__ unsigned short Bl[2][64 * BK];   // 8 KB each buf

    const int job = blockIdx.y;
    const float* adj = job == 0 ? A0 : job == 1 ? A1 : job == 2 ? A2 : job == 3 ? A3 : A4;
    const unsigned short* hT = (job < split) ? hTa : hTb;
    float* C = outBase + (size_t)job * (NODES * 64);
    const bool doTanh = (tanhMask >> job) & 1u;

    const int t = threadIdx.x;
    const int row0 = blockIdx.x * 16;

    // staging maps (exact covers, coalesced)
    const int ar = t >> 4, ak = (t & 15) * 4;     // A: 16 rows x 64 k f32, 4 f32/thread
    const int br = t >> 2, bk = (t & 3) * 16;     // B: 64 d  x 64 k bf16, 16 bf16/thread
    const float* ap = adj + (size_t)(row0 + ar) * NODES + ak;
    const unsigned short* bpt = hT + (size_t)br * NODES + bk;
    const int aoff  = ((ar * 128 + ak * 2) ^ ((ar & 7) << 4)) >> 1;
    const int boff0 = ((br * 128 + bk * 2) ^ ((br & 7) << 4)) >> 1;
    const int boff1 = ((br * 128 + bk * 2 + 16) ^ ((br & 7) << 4)) >> 1;

    // fragment offsets
    const int lane = t & 63, wid = t >> 6;
    const int fr = lane & 15, fg = lane >> 4;
    const int c0 = wid * 16;
    int afo[2], bfo[2];
#pragma unroll
    for (int s = 0; s < 2; ++s) {
        const int kk = (s * 32 + fg * 8) * 2;
        afo[s] = ((fr * 128 + kk) ^ ((fr & 7) << 4)) >> 1;
        const int dr = c0 + fr;
        bfo[s] = ((dr * 128 + kk) ^ ((dr & 7) << 4)) >> 1;
    }

    f32x4 acc = {0.f, 0.f, 0.f, 0.f};

    // prologue: tile 0
    f32x4 av = *(const f32x4*)ap;
    u16x8 bv0 = *(const u16x8*)bpt;
    u16x8 bv1 = *(const u16x8*)(bpt + 8);
    ap += BK; bpt += BK;
    {
        u16x4 pk = { f2bf(av[0]), f2bf(av[1]), f2bf(av[2]), f2bf(av[3]) };
        *(u16x4*)(&Al[0][aoff]) = pk;
        *(u16x8*)(&Bl[0][boff0]) = bv0;
        *(u16x8*)(&Bl[0][boff1]) = bv1;
    }
    __syncthreads();

    int cur = 0;
    for (int kt = 0; kt < NT; ++kt) {
        f32x4 na; u16x8 nb0, nb1;
        const bool more = (kt + 1 < NT);
        if (more) {                      // issue next-tile loads before compute (latency hides)
            na  = *(const f32x4*)ap;
            nb0 = *(const u16x8*)bpt;
            nb1 = *(const u16x8*)(bpt + 8);
            ap += BK; bpt += BK;
        }
#pragma unroll
        for (int s = 0; s < 2; ++s) {
            u16x8 a16 = *(const u16x8*)(&Al[cur][afo[s]]);
            u16x8 b16 = *(const u16x8*)(&Bl[cur][bfo[s]]);
            acc = __builtin_amdgcn_mfma_f32_16x16x32_bf16(
                __builtin_bit_cast(bf16x8, a16), __builtin_bit_cast(bf16x8, b16), acc, 0, 0, 0);
        }
        if (more) {
            const int nx = cur ^ 1;
            u16x4 pk = { f2bf(na[0]), f2bf(na[1]), f2bf(na[2]), f2bf(na[3]) };
            *(u16x4*)(&Al[nx][aoff]) = pk;
            *(u16x8*)(&Bl[nx][boff0]) = nb0;
            *(u16x8*)(&Bl[nx][boff1]) = nb1;
        }
        __syncthreads();
        cur ^= 1;
    }

    // C/D layout (m89-verified): col = lane&15, row = (lane>>4)*4 + j
    float* Cw = C + (size_t)(row0 + fg * 4) * 64 + c0 + fr;
#pragma unroll
    for (int j = 0; j < 4; ++j) {
        float v = acc[j];
        if (doTanh) v = tanhf(v);
        Cw[(size_t)j * 64] = v;
    }
}

// ---- stage C: semantic-attention logits (atomic) + schema softmax -> iccT bf16 [64][4096]
__global__ __launch_bounds__(128) void stage_c(
    const float* __restrict__ agg, const float* __restrict__ Wa,
    const float* __restrict__ ba, const float* __restrict__ qa,
    const float* __restrict__ wsv, float* __restrict__ sacc,
    unsigned short* __restrict__ iccT)
{
    const int n = blockIdx.x;
    const int p = threadIdx.x;          // 0..127 = PROJ lanes
    __shared__ float rs[3][2];
    __shared__ float ru[2][2];

    const float* h0p = agg + (size_t)n * 64;                       // hr[0]
    const float* h1p = agg + ((size_t)NODES + n) * 64;             // hr[1]
    const float* h2p = agg + ((size_t)2 * NODES + n) * 64;         // hr[2]
    float a0 = ba[p], a1 = a0, a2 = a0;
#pragma unroll 8
    for (int d = 0; d < 64; ++d) {
        float w = Wa[d * 128 + p];
        a0 = fmaf(h0p[d], w, a0);
        a1 = fmaf(h1p[d], w, a1);
        a2 = fmaf(h2p[d], w, a2);
    }
    float qv = qa[p];
    float v0 = tanhf(a0) * qv, v1 = tanhf(a1) * qv, v2 = tanhf(a2) * qv;

    const float* z0 = agg + ((size_t)3 * NODES + n) * 64;          // zk[0]
    const float* z1 = agg + ((size_t)4 * NODES + n) * 64;          // zk[1]
    float u0 = (p < 64) ? z0[p] * wsv[p] : 0.f;
    float u1 = (p < 64) ? z1[p] * wsv[p] : 0.f;

#pragma unroll
    for (int off = 32; off; off >>= 1) {
        v0 += __shfl_down(v0, off); v1 += __shfl_down(v1, off); v2 += __shfl_down(v2, off);
        u0 += __shfl_down(u0, off); u1 += __shfl_down(u1, off);
    }
    if ((p & 63) == 0) {
        int w = p >> 6;
        rs[0][w] = v0; rs[1][w] = v1; rs[2][w] = v2;
        ru[0][w] = u0; ru[1][w] = u1;
    }
    __syncthreads();
    if (p < 3) atomicAdd(&sacc[p], rs[p][0] + rs[p][1]);

    float U0 = ru[0][0] + ru[0][1];
    float U1 = ru[1][0] + ru[1][1];
    float mx = fmaxf(U0, U1);
    float e0 = expf(U0 - mx), e1 = expf(U1 - mx);
    float inv = 1.f / (e0 + e1);
    if (p < 64) {
        float icc = (e0 * z0[p] + e1 * z1[p]) * inv;
        iccT[(size_t)p * NODES + n] = f2bf(icc);
    }
}

// ---- stage E: relation_agg, item-item attention, AggAttention, projection ----
__global__ __launch_bounds__(256) void finalize(
    const float* __restrict__ agg, const float* __restrict__ ym,
    const float* __restrict__ sacc,
    const float* __restrict__ Wc1, const float* __restrict__ bc1, const float* __restrict__ wc2,
    const float* __restrict__ Wt1, const float* __restrict__ bt1, const float* __restrict__ wt2,
    const float* __restrict__ Wp, const float* __restrict__ bp,
    float* __restrict__ out)
{
    __shared__ float sWc[64 * 128];
    __shared__ float sWp[64 * 16];
    __shared__ float sHs0[2][64], sHs1[2][64], sHv[2][64];
    __shared__ float rA[2][2], rB[2][2];

    const int t = threadIdx.x;
    for (int i = t; i < 64 * 128; i += 256) sWc[i] = Wc1[i];
    for (int i = t; i < 64 * 16; i += 256) sWp[i] = Wp[i];

    float s0 = sacc[0] * (1.f / NODES), s1 = sacc[1] * (1.f / NODES), s2 = sacc[2] * (1.f / NODES);
    float sm = fmaxf(s0, fmaxf(s1, s2));
    float b0 = expf(s0 - sm), b1 = expf(s1 - sm), b2 = expf(s2 - sm);
    float bi = 1.f / (b0 + b1 + b2);
    b0 *= bi; b1 *= bi; b2 *= bi;

    const int sub = t >> 7;       // 2 nodes processed in parallel
    const int p = t & 127;
    const int wiH = p >> 6;
    const float bcv = bc1[p], wcv = wc2[p], btv = bt1[p], wtv = wt2[p];
    __syncthreads();

    for (int it = 0; it < 8; ++it) {
        const int n = blockIdx.x * 16 + it * 2 + sub;
        const float* y0 = ym + (size_t)n * 64;
        const float* y1 = ym + ((size_t)NODES + n) * 64;
        if (p < 64) {
            sHs0[sub][p] = b0 * agg[(size_t)n * 64 + p]
                         + b1 * agg[((size_t)NODES + n) * 64 + p]
                         + b2 * agg[((size_t)2 * NODES + n) * 64 + p];
        }
        float ac0 = bcv, ac1 = bcv;
#pragma unroll 8
        for (int d = 0; d < 64; ++d) {
            float w = sWc[d * 128 + p];
            ac0 = fmaf(y0[d], w, ac0);
            ac1 = fmaf(y1[d], w, ac1);
        }
        float v0 = tanhf(ac0) * wcv, v1 = tanhf(ac1) * wcv;
#pragma unroll
        for (int off = 32; off; off >>= 1) { v0 += __shfl_down(v0, off); v1 += __shfl_down(v1, off); }
        if ((p & 63) == 0) { rA[sub][wiH] = v0; rB[sub][wiH] = v1; }
        __syncthreads();
        float wm0 = rA[sub][0] + rA[sub][1];
        float wm1 = rB[sub][0] + rB[sub][1];
        float mm = fmaxf(wm0, wm1);
        float g0 = expf(wm0 - mm), g1 = expf(wm1 - mm);
        float gi = 1.f / (g0 + g1);
        g0 *= gi; g1 *= gi;
        if (p < 64) sHs1[sub][p] = g0 * y0[p] + g1 * y1[p];
        __syncthreads();

        float at0 = btv, at1 = btv;
#pragma unroll 8
        for (int d = 0; d < 64; ++d) {
            float w = Wt1[d * 128 + p];
            at0 = fmaf(sHs0[sub][d], w, at0);
            at1 = fmaf(sHs1[sub][d], w, at1);
        }
        float q0 = tanhf(at0) * wtv, q1 = tanhf(at1) * wtv;
#pragma unroll
        for (int off = 32; off; off >>= 1) { q0 += __shfl_down(q0, off); q1 += __shfl_down(q1, off); }
        if ((p & 63) == 0) { rA[sub][wiH] = q0; rB[sub][wiH] = q1; }
        __syncthreads();
        float t0 = rA[sub][0] + rA[sub][1];
        float t1 = rB[sub][0] + rB[sub][1];
        float tm = fmaxf(t0, t1);
        float c0 = expf(t0 - tm), c1 = expf(t1 - tm);
        float ci = 1.f / (c0 + c1);
        c0 *= ci; c1 *= ci;
        if (p < 64) {
            float H = c0 * sHs0[sub][p] + c1 * sHs1[sub][p];
            sHv[sub][p] = H;
            out[(size_t)NODES * 16 + (size_t)n * 64 + p] = H;
        }
        __syncthreads();
        if (p < 16) {
            float a = bp[p];
#pragma unroll 8
            for (int d = 0; d < 64; ++d) a = fmaf(sHv[sub][d], sWp[d * 16 + p], a);
            out[(size_t)n * 16 + p] = a;
        }
        __syncthreads();
    }
}

extern "C" void kernel_launch(void* const* d_in, const int* in_sizes, int n_in,
                              void* d_out, int out_size, void* d_ws, size_t ws_size,
                              hipStream_t stream)
{
    const float* f0   = (const float*)d_in[0];
    const float* f1   = (const float*)d_in[1];
    const float* adjS = (const float*)d_in[2];
    const float* adjM = (const float*)d_in[3];
    const float* adjK = (const float*)d_in[4];
    const float* Wm0  = (const float*)d_in[5];
    const float* bm0  = (const float*)d_in[6];
    const float* Wm1  = (const float*)d_in[7];
    const float* bm1  = (const float*)d_in[8];
    const float* Wa   = (const float*)d_in[9];
    const float* ba   = (const float*)d_in[10];
    const float* qa   = (const float*)d_in[11];
    const float* wsv  = (const float*)d_in[12];
    const float* Wc1  = (const float*)d_in[13];
    const float* bc1  = (const float*)d_in[14];
    const float* wc2  = (const float*)d_in[15];
    const float* Wt1  = (const float*)d_in[16];
    const float* bt1  = (const float*)d_in[17];
    const float* wt2  = (const float*)d_in[18];
    const float* Wp   = (const float*)d_in[19];
    const float* bpv  = (const float*)d_in[20];
    float* out = (float*)d_out;

    char* ws = (char*)d_ws;
    unsigned short* hT0  = (unsigned short*)(ws);                    // 512 KB
    unsigned short* hT1  = (unsigned short*)(ws + (512u << 10));     // 512 KB
    float* agg           = (float*)(ws + (1024u << 10));             // [5][4096][64] f32 = 5 MB
    unsigned short* iccT = (unsigned short*)(ws + (6144u << 10));    // 512 KB
    float* ym            = (float*)(ws + (6656u << 10));             // [2][4096][64] f32 = 2 MB
    float* sacc          = (float*)(ws + (8704u << 10));             // 3 floats

    hipMemsetAsync(sacc, 0, 64, stream);
    prep_h<<<dim3(1024), dim3(256), 0, stream>>>(f0, f1, Wm0, bm0, Wm1, bm1, hT0, hT1);

    const size_t NNs = (size_t)NODES * NODES;
    // jobs: hr[0..2] = tanh(adj_meta[r] @ h0), zk[0..1] = adj_schema[k] @ h1
    adj_gemm<<<dim3(256, 5), dim3(256), 0, stream>>>(
        adjM, adjM + NNs, adjM + 2 * NNs, adjK, adjK + NNs,
        hT0, hT1, 3, agg, 0x7u);
    stage_c<<<dim3(4096), dim3(128), 0, stream>>>(agg, Wa, ba, qa, wsv, sacc, iccT);
    // ym[m] = tanh(adj_same[m] @ icc)
    adj_gemm<<<dim3(256, 2), dim3(256), 0, stream>>>(
        adjS, adjS + NNs, adjS, adjS, adjS,
        iccT, iccT, 5, ym, 0x3u);
    finalize<<<dim3(256), dim3(256), 0, stream>>>(
        agg, ym, sacc, Wc1, bc1, wc2, Wt1, bt1, wt2, Wp, bpv, out);
}